// Round 4
// baseline (442.824 us; speedup 1.0000x reference)
//
#include <hip/hip_runtime.h>

typedef _Float16 half8 __attribute__((ext_vector_type(8)));
typedef float floatx4 __attribute__((ext_vector_type(4)));

__device__ __forceinline__ float fast_sigmoid(float x) {
    return __builtin_amdgcn_rcpf(1.0f + __expf(-x));
}
__device__ __forceinline__ float fast_tanh(float x) {
    return 1.0f - 2.0f * __builtin_amdgcn_rcpf(__expf(2.0f * x) + 1.0f);
}

// Barrier that does NOT drain vmem (verified r2->r3): only LDS ops published.
// 0xC07F = vmcnt(63) expcnt(7) lgkmcnt(0).
template<bool MULTI_WAVE>
__device__ __forceinline__ void lds_publish_barrier() {
    asm volatile("" ::: "memory");
    __builtin_amdgcn_s_waitcnt(0xC07F);
    if constexpr (MULTI_WAVE) __builtin_amdgcn_s_barrier();
    asm volatile("" ::: "memory");
}

// ---------- x -> padded f16 (kills fp32 bounds-checked gathers in hot loops)
__global__ __launch_bounds__(256)
void cvt_x(const float* __restrict__ x, _Float16* __restrict__ x16)
{
    const long gid  = (long)blockIdx.x * 256 + threadIdx.x;   // 1,572,864 threads
    const long base = gid * 8;                                // 8 f16 per thread
    const long row  = base / 96;
    const int  k0   = (int)(base % 96);
    half8 v;
    #pragma unroll
    for (int j = 0; j < 8; j++) {
        const int k = k0 + j;
        v[j] = (k < 78) ? (_Float16)x[row * 78 + k] : (_Float16)0;
    }
    *(half8*)(x16 + base) = v;
}

// ---------- xz GEMM: z = in @ Wk + b, gate-sliced cols, stored f16 in the
// exact C-fragment record the recurrence lane consumes (32 B contiguous).
// M-tile = 16 rows = 8 chains x 2 timesteps -> zero dead rows. No LDS.
// Record: xz[((dir*128+bg)*T + t)*NW + w][q2][l16][g*4+r] f16.
template<int F_REAL, int FP, int U>
__global__ __launch_bounds__(64 * (U / 16))
void xz_gemm(const _Float16* __restrict__ in,   // rows of FP f16, row = b*T + t_x
             const float* __restrict__ Wk_f, const float* __restrict__ b_f,
             const float* __restrict__ Wk_b, const float* __restrict__ b_b,
             _Float16* __restrict__ xz)
{
    constexpr int T  = 128;
    constexpr int XT = FP / 32;
    constexpr int NW = U / 16;
    constexpr int N  = 4 * U;

    const int tid  = threadIdx.x;
    const int wave = tid >> 6;
    const int lane = tid & 63;
    const int quad = lane >> 4;
    const int l16  = lane & 15;

    const int bg  = blockIdx.x & 127;
    const int dir = (blockIdx.x >> 7) & 1;
    const int tc  = blockIdx.x >> 8;          // 8 chunks of 8 t-pairs

    const float* Wk = dir ? Wk_b : Wk_f;
    const float* bs = dir ? b_b  : b_f;

    const int ucol = wave * 16 + l16;
    half8 bf[4][XT];
    #pragma unroll
    for (int g = 0; g < 4; g++) {
        const int n = g * U + ucol;
        #pragma unroll
        for (int kt = 0; kt < XT; kt++) {
            half8 h;
            #pragma unroll
            for (int j = 0; j < 8; j++) {
                const int k = kt * 32 + quad * 8 + j;
                h[j] = (k < F_REAL) ? (_Float16)Wk[k * N + n] : (_Float16)0;
            }
            bf[g][kt] = h;
        }
    }
    float bias[4];
    #pragma unroll
    for (int g = 0; g < 4; g++) bias[g] = bs[g * U + ucol];

    // A row m = l16 -> chain (l16&7), t = 2tp + (l16>>3)
    const int brow = bg * 8 + (l16 & 7);
    const int tsel_a = l16 >> 3;
    // C rows quad*4+r -> chain (quad&1)*4+r, t = 2tp + (quad>>1)
    const int q2 = quad & 1;
    const int tsel_c = quad >> 1;

    for (int tp = tc * 8; tp < tc * 8 + 8; tp++) {
        const int t_a = 2 * tp + tsel_a;
        const int t_x = dir ? (T - 1 - t_a) : t_a;
        const _Float16* ap = in + ((long)brow * T + t_x) * FP;

        floatx4 acc[4];
        #pragma unroll
        for (int g = 0; g < 4; g++) {
            floatx4 v = {bias[g], bias[g], bias[g], bias[g]};
            acc[g] = v;
        }
        #pragma unroll
        for (int kt = 0; kt < XT; kt++) {
            const half8 a = *(const half8*)(ap + kt * 32 + quad * 8);
            #pragma unroll
            for (int g = 0; g < 4; g++)
                acc[g] = __builtin_amdgcn_mfma_f32_16x16x32_f16(a, bf[g][kt], acc[g], 0, 0, 0);
        }
        // pack 16 f32 -> 16 f16, one 32B store per lane
        half8 lo, hi;
        #pragma unroll
        for (int r = 0; r < 4; r++) {
            lo[r]     = (_Float16)acc[0][r];
            lo[4 + r] = (_Float16)acc[1][r];
            hi[r]     = (_Float16)acc[2][r];
            hi[4 + r] = (_Float16)acc[3][r];
        }
        const int t_c = 2 * tp + tsel_c;
        _Float16* op = xz + (((((long)(dir * 128 + bg) * T + t_c) * NW + wave) * 2 + q2) * 256 + l16 * 16);
        *(half8*)op       = lo;
        *(half8*)(op + 8) = hi;
    }
}

// ---------- recurrence: only h@Wr + gates on the serial path.
// acc init = prefetched xz record (bias folded). One lgkm-only barrier/step.
template<int U, int HT, bool SEQ_OUT>
__global__ __launch_bounds__(64 * (U / 16))
void lstm_rec(const _Float16* __restrict__ xz,
              const float* __restrict__ Wr_f, const float* __restrict__ Wr_b,
              _Float16* __restrict__ hseq, float* __restrict__ hlast)
{
    constexpr int T    = 128;
    constexpr int N    = 4 * U;
    constexpr int NW   = U / 16;
    constexpr int HROW = HT * 32 + 8;        // f16/row, 16B-aligned, bank-skewed
    constexpr int THREADS = NW * 64;

    const int tid  = threadIdx.x;
    const int wave = tid >> 6;
    const int lane = tid & 63;
    const int quad = lane >> 4;
    const int l16  = lane & 15;

    const int dir   = blockIdx.x >> 7;
    const int bg    = blockIdx.x & 127;
    const int bbase = bg * 8;

    const float* Wr = dir ? Wr_b : Wr_f;

    __shared__ __align__(16) _Float16 H[2][16][HROW];
    for (int i = tid; i < 2 * 16 * HROW; i += THREADS)
        (&H[0][0][0])[i] = (_Float16)0;      // h0=0; rows 8..15, pad, u>=U stay 0

    const int ucol = wave * 16 + l16;
    half8 bf[4][HT];
    #pragma unroll
    for (int g = 0; g < 4; g++) {
        const int n = g * U + ucol;
        #pragma unroll
        for (int ht = 0; ht < HT; ht++) {
            half8 h;
            #pragma unroll
            for (int j = 0; j < 8; j++) {
                const int k = ht * 32 + quad * 8 + j;
                h[j] = (k < U) ? (_Float16)Wr[k * N + n] : (_Float16)0;
            }
            bf[g][ht] = h;
        }
    }

    const int rowbase = (quad & 1) * 4 + (quad >> 1) * 2;   // r3-verified mapping
    float c_reg[2] = {0.0f, 0.0f};

    const long rec_base = ((long)(dir * 128 + bg) * T) * (NW * 512)
                        + ((long)wave * 2 + (quad & 1)) * 256 + l16 * 16;

    auto load_xz = [&](int t, half8* z) {
        const int tc = t < T ? t : T - 1;
        const _Float16* p = xz + rec_base + (long)tc * (NW * 512);
        z[0] = *(const half8*)p;
        z[1] = *(const half8*)(p + 8);
    };

    auto step = [&](int t, half8* z) {
        // acc init from prefetched raw f16 record (loaded 2 steps ago)
        floatx4 acc[4];
        #pragma unroll
        for (int g = 0; g < 4; g++) {
            #pragma unroll
            for (int r = 0; r < 4; r++)
                acc[g][r] = (float)z[g >> 1][(g & 1) * 4 + r];
        }
        load_xz(t + 2, z);                   // stays in flight across barrier
        lds_publish_barrier<(NW > 1)>();
        const _Float16* hb = &H[t & 1][l16][0];
        #pragma unroll
        for (int ht = 0; ht < HT; ht++) {
            const half8 ha = *(const half8*)(hb + ht * 32 + quad * 8);
            #pragma unroll
            for (int g = 0; g < 4; g++)
                acc[g] = __builtin_amdgcn_mfma_f32_16x16x32_f16(ha, bf[g][ht], acc[g], 0, 0, 0);
        }
        // redistribute rows 2,3/6,7 to quads 2,3 (r3-verified)
        float zz[4][2];
        #pragma unroll
        for (int g = 0; g < 4; g++) {
            #pragma unroll
            for (int s = 0; s < 2; s++) {
                const float hi = __shfl_xor(acc[g][2 + s], 32, 64);
                zz[g][s] = (quad < 2) ? acc[g][s] : hi;
            }
        }
        float hq[2];
        #pragma unroll
        for (int s = 0; s < 2; s++) {
            const float ig = fast_sigmoid(zz[0][s]);
            const float fg = fast_sigmoid(zz[1][s]);
            const float gg = fast_tanh(zz[2][s]);
            const float og = fast_sigmoid(zz[3][s]);
            const float c  = fg * c_reg[s] + ig * gg;
            c_reg[s] = c;
            hq[s] = og * fast_tanh(c);
        }
        #pragma unroll
        for (int s = 0; s < 2; s++)
            H[(t + 1) & 1][rowbase + s][ucol] = (_Float16)hq[s];
        if constexpr (SEQ_OUT) {
            const int tp = dir ? (T - 1 - t) : t;
            #pragma unroll
            for (int s = 0; s < 2; s++)
                hseq[((long)(bbase + rowbase + s) * T + tp) * (2 * U) + dir * U + ucol] = (_Float16)hq[s];
        } else {
            if (t == T - 1) {
                #pragma unroll
                for (int s = 0; s < 2; s++)
                    hlast[(bbase + rowbase + s) * (2 * U) + dir * U + ucol] = hq[s];
            }
        }
    };

    half8 za[2], zb[2];
    load_xz(0, za);
    load_xz(1, zb);
    __syncthreads();                          // H zero-init visible (once)

    for (int tt = 0; tt < T; tt += 2) {
        step(tt,     za);
        step(tt + 1, zb);
    }
}

__global__ __launch_bounds__(256)
void dense_head(const float* __restrict__ h3,
                const float* __restrict__ w1, const float* __restrict__ b1,
                const float* __restrict__ w2, const float* __restrict__ b2,
                float* __restrict__ out)
{
    const int r = blockIdx.x * 256 + threadIdx.x;
    if (r >= 1024) return;
    float h[32];
    #pragma unroll
    for (int k = 0; k < 32; k++) h[k] = h3[r * 32 + k];
    float d1[8];
    #pragma unroll
    for (int j = 0; j < 8; j++) {
        float a = b1[j];
        #pragma unroll
        for (int k = 0; k < 32; k++) a += h[k] * w1[k * 8 + j];
        d1[j] = fmaxf(a, 0.0f);
    }
    #pragma unroll
    for (int c = 0; c < 3; c++) {
        float s = b2[c];
        #pragma unroll
        for (int j = 0; j < 8; j++) s += d1[j] * w2[j * 3 + c];
        out[r * 3 + c] = 1.0f / (1.0f + __expf(-s));
    }
}

extern "C" void kernel_launch(void* const* d_in, const int* in_sizes, int n_in,
                              void* d_out, int out_size, void* d_ws, size_t ws_size,
                              hipStream_t stream) {
    const float* x     = (const float*)d_in[0];
    const float* w1f_k = (const float*)d_in[1];
    const float* w1f_r = (const float*)d_in[2];
    const float* w1f_b = (const float*)d_in[3];
    const float* w1b_k = (const float*)d_in[4];
    const float* w1b_r = (const float*)d_in[5];
    const float* w1b_b = (const float*)d_in[6];
    const float* w2f_k = (const float*)d_in[7];
    const float* w2f_r = (const float*)d_in[8];
    const float* w2f_b = (const float*)d_in[9];
    const float* w2b_k = (const float*)d_in[10];
    const float* w2b_r = (const float*)d_in[11];
    const float* w2b_b = (const float*)d_in[12];
    const float* w3f_k = (const float*)d_in[13];
    const float* w3f_r = (const float*)d_in[14];
    const float* w3f_b = (const float*)d_in[15];
    const float* w3b_k = (const float*)d_in[16];
    const float* w3b_r = (const float*)d_in[17];
    const float* w3b_b = (const float*)d_in[18];
    const float* d3_w  = (const float*)d_in[19];
    const float* d3_b  = (const float*)d_in[20];
    const float* cls_w = (const float*)d_in[21];
    const float* cls_b = (const float*)d_in[22];

    char* ws = (char*)d_ws;
    // Arena A (reused 3x): xz1 134.2MB -> xz2 67.1MB -> xz3 33.6MB
    _Float16* xz = (_Float16*)ws;
    // Arena B: x16 (25.2MB) during G1, then h1 (32MB) from R1 onward
    _Float16* x16 = (_Float16*)(ws + 134217728);
    _Float16* h1  = (_Float16*)(ws + 134217728);
    // Arena C: h2 (16.8MB) + h3
    _Float16* h2 = (_Float16*)(ws + 134217728 + 33554432);
    float*    h3 = (float*)   (ws + 134217728 + 33554432 + 16777216);

    // x -> padded f16 [b][t][96]
    cvt_x<<<dim3(6144), dim3(256), 0, stream>>>(x, x16);

    // L1: F=78 (pad 96), U=64
    xz_gemm<78, 96, 64><<<dim3(2048), dim3(256), 0, stream>>>(
        x16, w1f_k, w1f_b, w1b_k, w1b_b, xz);
    lstm_rec<64, 2, true><<<dim3(256), dim3(256), 0, stream>>>(
        xz, w1f_r, w1b_r, h1, nullptr);

    // L2: F=128, U=32
    xz_gemm<128, 128, 32><<<dim3(2048), dim3(128), 0, stream>>>(
        h1, w2f_k, w2f_b, w2b_k, w2b_b, xz);
    lstm_rec<32, 1, true><<<dim3(256), dim3(128), 0, stream>>>(
        xz, w2f_r, w2b_r, h2, nullptr);

    // L3: F=64, U=16 (K padded to 32 with zeros)
    xz_gemm<64, 64, 16><<<dim3(2048), dim3(64), 0, stream>>>(
        h2, w3f_k, w3f_b, w3b_k, w3b_b, xz);
    lstm_rec<16, 1, false><<<dim3(256), dim3(64), 0, stream>>>(
        xz, w3f_r, w3b_r, nullptr, h3);

    dense_head<<<dim3(4), dim3(256), 0, stream>>>(h3, d3_w, d3_b, cls_w, cls_b, (float*)d_out);
}

// Round 5
// 429.444 us; speedup vs baseline: 1.0312x; 1.0312x over previous
//
#include <hip/hip_runtime.h>

typedef _Float16 half8 __attribute__((ext_vector_type(8)));
typedef float floatx4 __attribute__((ext_vector_type(4)));

__device__ __forceinline__ float fast_sigmoid(float x) {
    return __builtin_amdgcn_rcpf(1.0f + __expf(-x));
}
__device__ __forceinline__ float fast_tanh(float x) {
    return 1.0f - 2.0f * __builtin_amdgcn_rcpf(__expf(2.0f * x) + 1.0f);
}

// Barrier that does NOT drain vmem (verified r2->r3): only LDS ops published.
// 0xC07F = vmcnt(63) expcnt(7) lgkmcnt(0).
template<bool MULTI_WAVE>
__device__ __forceinline__ void lds_publish_barrier() {
    asm volatile("" ::: "memory");
    __builtin_amdgcn_s_waitcnt(0xC07F);
    if constexpr (MULTI_WAVE) __builtin_amdgcn_s_barrier();
    asm volatile("" ::: "memory");
}

// ---------- xz GEMM: z = in @ Wk + b, gate-sliced cols, stored f16 in the
// exact C-fragment record the recurrence lane consumes (32 B contiguous).
// M-tile = 16 rows = 8 chains x 2 timesteps. No LDS. Weight preamble
// amortized over TPC t-pairs per block.
// Record: xz[((dir*128+bg)*T + t)*NW + w][q2][l16][g*4+r] f16.
template<int F_REAL, int XT, int U, bool IN_F32, int TPC>
__global__ __launch_bounds__(64 * (U / 16))
void xz_gemm(const void* __restrict__ in_,    // rows of F_REAL elems, row = b*T + t_x
             const float* __restrict__ Wk_f, const float* __restrict__ b_f,
             const float* __restrict__ Wk_b, const float* __restrict__ b_b,
             _Float16* __restrict__ xz)
{
    constexpr int T  = 128;
    constexpr int NW = U / 16;
    constexpr int N  = 4 * U;

    const int tid  = threadIdx.x;
    const int wave = tid >> 6;
    const int lane = tid & 63;
    const int quad = lane >> 4;
    const int l16  = lane & 15;

    const int bg  = blockIdx.x & 127;
    const int dir = (blockIdx.x >> 7) & 1;
    const int tc  = blockIdx.x >> 8;

    const float* Wk = dir ? Wk_b : Wk_f;
    const float* bs = dir ? b_b  : b_f;

    const int ucol = wave * 16 + l16;
    half8 bf[4][XT];
    #pragma unroll
    for (int g = 0; g < 4; g++) {
        const int n = g * U + ucol;
        #pragma unroll
        for (int kt = 0; kt < XT; kt++) {
            half8 h;
            #pragma unroll
            for (int j = 0; j < 8; j++) {
                const int k = kt * 32 + quad * 8 + j;
                h[j] = (k < F_REAL) ? (_Float16)Wk[k * N + n] : (_Float16)0;
            }
            bf[g][kt] = h;
        }
    }
    float bias[4];
    #pragma unroll
    for (int g = 0; g < 4; g++) bias[g] = bs[g * U + ucol];

    // A row m = l16 -> chain (l16&7), t = 2tp + (l16>>3)
    const int brow   = bg * 8 + (l16 & 7);
    const int tsel_a = l16 >> 3;
    // C rows quad*4+r -> chain (quad&1)*4+r, t = 2tp + (quad>>1)
    const int q2     = quad & 1;
    const int tsel_c = quad >> 1;

    for (int tp = tc * TPC; tp < tc * TPC + TPC; tp++) {
        const int t_a = 2 * tp + tsel_a;
        const int t_x = dir ? (T - 1 - t_a) : t_a;

        floatx4 acc[4];
        #pragma unroll
        for (int g = 0; g < 4; g++) {
            floatx4 v = {bias[g], bias[g], bias[g], bias[g]};
            acc[g] = v;
        }
        #pragma unroll
        for (int kt = 0; kt < XT; kt++) {
            const int kb = kt * 32 + quad * 8;
            half8 a;
            if constexpr (IN_F32) {
                const float* p = (const float*)in_ + ((long)brow * T + t_x) * F_REAL;
                #pragma unroll
                for (int j = 0; j < 8; j += 2) {
                    const int k = kb + j;
                    float v0 = 0.0f, v1 = 0.0f;
                    if (k + 2 <= F_REAL) { const float2 v = *(const float2*)(p + k); v0 = v.x; v1 = v.y; }
                    else if (k < F_REAL) { v0 = p[k]; }
                    a[j] = (_Float16)v0; a[j + 1] = (_Float16)v1;
                }
            } else {
                const _Float16* p = (const _Float16*)in_ + ((long)brow * T + t_x) * F_REAL;
                a = *(const half8*)(p + kb);   // F_REAL % 32 == 0 for f16 inputs
            }
            #pragma unroll
            for (int g = 0; g < 4; g++)
                acc[g] = __builtin_amdgcn_mfma_f32_16x16x32_f16(a, bf[g][kt], acc[g], 0, 0, 0);
        }
        half8 lo, hi;
        #pragma unroll
        for (int r = 0; r < 4; r++) {
            lo[r]     = (_Float16)acc[0][r];
            lo[4 + r] = (_Float16)acc[1][r];
            hi[r]     = (_Float16)acc[2][r];
            hi[4 + r] = (_Float16)acc[3][r];
        }
        const int t_c = 2 * tp + tsel_c;
        _Float16* op = xz + (((((long)(dir * 128 + bg) * T + t_c) * NW + wave) * 2 + q2) * 256 + l16 * 16);
        *(half8*)op       = lo;
        *(half8*)(op + 8) = hi;
    }
}

// ---------- recurrence: only h@Wr + gates on the serial path.
// A rows 8..15 duplicate rows 0..7 (ds_read H[l16&7], same-address broadcast)
// so quads 2,3 natively hold correct full z for chains 0..7 -> NO shuffles.
// Lane (quad) handles chains rowbase..rowbase+1; acc rows rowsel = same.
template<int U, int HT, bool SEQ_OUT>
__global__ __launch_bounds__(64 * (U / 16))
void lstm_rec(const _Float16* __restrict__ xz,
              const float* __restrict__ Wr_f, const float* __restrict__ Wr_b,
              _Float16* __restrict__ hseq, float* __restrict__ hlast)
{
    constexpr int T    = 128;
    constexpr int N    = 4 * U;
    constexpr int NW   = U / 16;
    constexpr int HROW = HT * 32 + 8;        // f16/row, 16B-aligned stride
    constexpr int THREADS = NW * 64;

    const int tid  = threadIdx.x;
    const int wave = tid >> 6;
    const int lane = tid & 63;
    const int quad = lane >> 4;
    const int l16  = lane & 15;

    const int dir   = blockIdx.x >> 7;
    const int bg    = blockIdx.x & 127;
    const int bbase = bg * 8;

    const float* Wr = dir ? Wr_b : Wr_f;

    __shared__ __align__(16) _Float16 H[2][8][HROW];
    for (int i = tid; i < 2 * 8 * HROW; i += THREADS)
        (&H[0][0][0])[i] = (_Float16)0;      // h0=0; pad and u>=U stay 0

    const int ucol = wave * 16 + l16;
    half8 bf[4][HT];
    #pragma unroll
    for (int g = 0; g < 4; g++) {
        const int n = g * U + ucol;
        #pragma unroll
        for (int ht = 0; ht < HT; ht++) {
            half8 h;
            #pragma unroll
            for (int j = 0; j < 8; j++) {
                const int k = ht * 32 + quad * 8 + j;
                h[j] = (k < U) ? (_Float16)Wr[k * N + n] : (_Float16)0;
            }
            bf[g][ht] = h;
        }
    }

    // quad -> 2 chains: q0:{0,1} q1:{4,5} q2:{2,3} q3:{6,7}; acc row = chain&3|...
    const int rowbase = (quad & 1) * 4 + (quad >> 1) * 2;   // chain base
    const bool hi_rows = (quad & 2) != 0;                    // acc rows 2,3 vs 0,1
    float c_reg[2] = {0.0f, 0.0f};

    const long rec_base = ((long)(dir * 128 + bg) * T) * (NW * 512)
                        + ((long)wave * 2 + (quad & 1)) * 256 + l16 * 16;

    auto load_xz = [&](int t, half8* z) {
        const int tc = t < T ? t : T - 1;
        const _Float16* p = xz + rec_base + (long)tc * (NW * 512);
        z[0] = *(const half8*)p;
        z[1] = *(const half8*)(p + 8);
    };

    // hseq pointer: per-step increment instead of full addressing
    const int tp0 = dir ? (T - 1) : 0;
    const long hs_stride = (long)T * (2 * U);
    _Float16* hs_ptr = SEQ_OUT
        ? hseq + ((long)(bbase + rowbase) * T + tp0) * (2 * U) + dir * U + ucol
        : nullptr;
    const long hs_delta = dir ? -(long)(2 * U) : (long)(2 * U);

    auto step = [&](int t, half8* z) {
        floatx4 acc[4];
        #pragma unroll
        for (int g = 0; g < 4; g++) {
            #pragma unroll
            for (int r = 0; r < 4; r++)
                acc[g][r] = (float)z[g >> 1][(g & 1) * 4 + r];
        }
        load_xz(t + 2, z);                   // stays in flight across barrier
        lds_publish_barrier<(NW > 1)>();
        const _Float16* hb = &H[t & 1][l16 & 7][0];   // rows 8..15 = dup of 0..7
        #pragma unroll
        for (int ht = 0; ht < HT; ht++) {
            const half8 ha = *(const half8*)(hb + ht * 32 + quad * 8);
            #pragma unroll
            for (int g = 0; g < 4; g++)
                acc[g] = __builtin_amdgcn_mfma_f32_16x16x32_f16(ha, bf[g][ht], acc[g], 0, 0, 0);
        }
        // gates: 2 chains per lane from this lane's OWN acc rows (no shuffles)
        float hq[2];
        #pragma unroll
        for (int s = 0; s < 2; s++) {
            const int r = hi_rows ? (2 + s) : s;
            const float ig = fast_sigmoid(acc[0][r]);
            const float fg = fast_sigmoid(acc[1][r]);
            const float gg = fast_tanh(acc[2][r]);
            const float og = fast_sigmoid(acc[3][r]);
            const float c  = fg * c_reg[s] + ig * gg;
            c_reg[s] = c;
            hq[s] = og * fast_tanh(c);
        }
        #pragma unroll
        for (int s = 0; s < 2; s++)
            H[(t + 1) & 1][rowbase + s][ucol] = (_Float16)hq[s];
        if constexpr (SEQ_OUT) {
            #pragma unroll
            for (int s = 0; s < 2; s++)
                hs_ptr[s * hs_stride] = (_Float16)hq[s];
            hs_ptr += hs_delta;
        } else {
            if (t == T - 1) {
                #pragma unroll
                for (int s = 0; s < 2; s++)
                    hlast[(bbase + rowbase + s) * (2 * U) + dir * U + ucol] = hq[s];
            }
        }
    };

    half8 za[2], zb[2];
    load_xz(0, za);
    load_xz(1, zb);
    __syncthreads();                          // H zero-init visible (once)

    for (int tt = 0; tt < T; tt += 2) {
        step(tt,     za);
        step(tt + 1, zb);
    }
}

__global__ __launch_bounds__(256)
void dense_head(const float* __restrict__ h3,
                const float* __restrict__ w1, const float* __restrict__ b1,
                const float* __restrict__ w2, const float* __restrict__ b2,
                float* __restrict__ out)
{
    const int r = blockIdx.x * 256 + threadIdx.x;
    if (r >= 1024) return;
    float h[32];
    #pragma unroll
    for (int k = 0; k < 32; k++) h[k] = h3[r * 32 + k];
    float d1[8];
    #pragma unroll
    for (int j = 0; j < 8; j++) {
        float a = b1[j];
        #pragma unroll
        for (int k = 0; k < 32; k++) a += h[k] * w1[k * 8 + j];
        d1[j] = fmaxf(a, 0.0f);
    }
    #pragma unroll
    for (int c = 0; c < 3; c++) {
        float s = b2[c];
        #pragma unroll
        for (int j = 0; j < 8; j++) s += d1[j] * w2[j * 3 + c];
        out[r * 3 + c] = 1.0f / (1.0f + __expf(-s));
    }
}

extern "C" void kernel_launch(void* const* d_in, const int* in_sizes, int n_in,
                              void* d_out, int out_size, void* d_ws, size_t ws_size,
                              hipStream_t stream) {
    const float* x     = (const float*)d_in[0];
    const float* w1f_k = (const float*)d_in[1];
    const float* w1f_r = (const float*)d_in[2];
    const float* w1f_b = (const float*)d_in[3];
    const float* w1b_k = (const float*)d_in[4];
    const float* w1b_r = (const float*)d_in[5];
    const float* w1b_b = (const float*)d_in[6];
    const float* w2f_k = (const float*)d_in[7];
    const float* w2f_r = (const float*)d_in[8];
    const float* w2f_b = (const float*)d_in[9];
    const float* w2b_k = (const float*)d_in[10];
    const float* w2b_r = (const float*)d_in[11];
    const float* w2b_b = (const float*)d_in[12];
    const float* w3f_k = (const float*)d_in[13];
    const float* w3f_r = (const float*)d_in[14];
    const float* w3f_b = (const float*)d_in[15];
    const float* w3b_k = (const float*)d_in[16];
    const float* w3b_r = (const float*)d_in[17];
    const float* w3b_b = (const float*)d_in[18];
    const float* d3_w  = (const float*)d_in[19];
    const float* d3_b  = (const float*)d_in[20];
    const float* cls_w = (const float*)d_in[21];
    const float* cls_b = (const float*)d_in[22];

    char* ws = (char*)d_ws;
    // Arena A (reused 3x): xz1 134.2MB -> xz2 67.1MB -> xz3 33.6MB
    _Float16* xz = (_Float16*)ws;
    _Float16* h1 = (_Float16*)(ws + 134217728);                  // 32MB
    _Float16* h2 = (_Float16*)(ws + 134217728 + 33554432);       // 16.8MB
    float*    h3 = (float*)   (ws + 134217728 + 33554432 + 16777216);

    // L1: F=78 (3 k-tiles, fp32 in), U=64
    xz_gemm<78, 3, 64, true, 16><<<dim3(1024), dim3(256), 0, stream>>>(
        x, w1f_k, w1f_b, w1b_k, w1b_b, xz);
    lstm_rec<64, 2, true><<<dim3(256), dim3(256), 0, stream>>>(
        xz, w1f_r, w1b_r, h1, nullptr);

    // L2: F=128, U=32
    xz_gemm<128, 4, 32, false, 16><<<dim3(1024), dim3(128), 0, stream>>>(
        h1, w2f_k, w2f_b, w2b_k, w2b_b, xz);
    lstm_rec<32, 1, true><<<dim3(256), dim3(128), 0, stream>>>(
        xz, w2f_r, w2b_r, h2, nullptr);

    // L3: F=64, U=16
    xz_gemm<64, 2, 16, false, 16><<<dim3(1024), dim3(64), 0, stream>>>(
        h2, w3f_k, w3f_b, w3b_k, w3b_b, xz);
    lstm_rec<16, 1, false><<<dim3(256), dim3(64), 0, stream>>>(
        xz, w3f_r, w3b_r, nullptr, h3);

    dense_head<<<dim3(4), dim3(256), 0, stream>>>(h3, d3_w, d3_b, cls_w, cls_b, (float*)d_out);
}